// Round 8
// baseline (279.326 us; speedup 1.0000x reference)
//
#include <hip/hip_runtime.h>

#define HID 256
#define LAT 128
#define VOC 32000
#define NSTEP 128

// ---------------- prep: wcomb (split-j) + block-transposed weight packs ------
__global__ __launch_bounds__(512)
void prep_kernel(const float* __restrict__ Wp, const float* __restrict__ W2,
                 const float* __restrict__ b2, const float* __restrict__ bp,
                 const float* __restrict__ Wpar,
                 const float* __restrict__ Wmu, const float* __restrict__ Wlv,
                 float* __restrict__ Wcomb, float* __restrict__ bcomb,
                 float* __restrict__ Wq_par, float* __restrict__ Wq_mu,
                 float* __restrict__ Wq_lv, float* __restrict__ Wq_w2,
                 int* __restrict__ bar) {
    const int b = blockIdx.x;
    const int t = threadIdx.x;
    if (b == 0 && t == 0) { bar[0] = 0; bar[1] = 0; }   // grid-barrier init
    if (b < 256) {                     // Wcomb row o = Wp_tail[o] @ W2[1:], bcomb[o]
        const int o = b;
        const int k = t & 255, jh = t >> 8;
        __shared__ float wpt_s[256];
        __shared__ float part_s[2][256];
        __shared__ float red_s[4];
        if (t < 256) wpt_s[t] = Wp[(size_t)(VOC + o) * HID + t];
        __syncthreads();
        float acc = 0.f;
#pragma unroll 8
        for (int j = 0; j < 128; j++)
            acc += wpt_s[jh * 128 + j] * W2[(size_t)(1 + jh * 128 + j) * HID + k];
        part_s[jh][k] = acc;
        if (t < 256) {
            float p = wpt_s[k] * b2[1 + k];
            p += __shfl_xor(p, 1);  p += __shfl_xor(p, 2);  p += __shfl_xor(p, 4);
            p += __shfl_xor(p, 8);  p += __shfl_xor(p, 16); p += __shfl_xor(p, 32);
            if ((k & 63) == 0) red_s[k >> 6] = p;
        }
        __syncthreads();
        if (t < 256) Wcomb[(size_t)o * HID + k] = part_s[0][k] + part_s[1][k];
        if (t == 0) bcomb[o] = bp[VOC + o] + red_s[0] + red_s[1] + red_s[2] + red_s[3];
    } else if (b < 352) {              // Wpar pack: 96 blocks x 2 k4
        const int k4 = (b - 256) * 2 + (t >> 8);
        const int r = t & 255;
        ((float4*)Wq_par)[k4 * 256 + r] = *(const float4*)(Wpar + (size_t)r * 768 + 4 * k4);
    } else if (b < 384) {              // Wmu/Wlv pack: 32 blocks x 2 k4
        const int k4 = (b - 352) * 2 + (t >> 8);
        const int r = t & 127, sel = (t >> 7) & 1;
        const float* src = (sel ? Wlv : Wmu) + (size_t)r * HID + 4 * k4;
        ((float4*)(sel ? Wq_lv : Wq_mu))[k4 * 128 + r] = *(const float4*)src;
    } else {                           // W2[1:] pack: 32 blocks x 2 k4
        const int k4 = (b - 384) * 2 + (t >> 8);
        const int r = t & 255;
        ((float4*)Wq_w2)[k4 * 256 + r] = *(const float4*)(W2 + (size_t)(1 + r) * HID + 4 * k4);
    }
}

// ---------------- fused two-level encoder (levels 8+7 -> h[63..126]) ---------
__global__ __launch_bounds__(1024)
void enc2(const float* __restrict__ embed, const int* __restrict__ values,
          const float* __restrict__ Wq, const float* __restrict__ bpar,
          float* __restrict__ h, int base) {
    const int i = base + blockIdx.x;
    const int t = threadIdx.x;
    const int o = t & 255;
    const int g = t >> 8;              // 0..3
    const int cid = g & 1, kh = g >> 1;
    __shared__ __align__(16) float cat[2][768];
    __shared__ float part[4][256];
    __shared__ __align__(16) float pcat[768];

    const int c0n = 2 * i + 1;
    for (int q = t; q < 1536; q += 1024) {
        const int cc = (q >= 768);
        const int e = q - cc * 768;
        const int node = c0n + cc;
        const int seg = e >> 8, idx = e & 255;
        float v;
        if (seg == 0) v = embed[(size_t)values[node] * HID + idx];
        else {
            const int ch = 2 * node + seg;
            v = (ch >= 255) ? embed[(size_t)values[ch] * HID + idx]
                            : h[(size_t)ch * HID + idx];
        }
        cat[cc][e] = v;
    }
    __syncthreads();
    {
        const float4* wq = (const float4*)Wq + o;
        const float4* c4 = (const float4*)cat[cid] + kh * 96;
        float s0 = 0.f, s1 = 0.f, s2 = 0.f, s3 = 0.f;
#pragma unroll 8
        for (int k4 = 0; k4 < 96; k4 += 4) {
            const float4 wa = wq[(size_t)(kh * 96 + k4) * 256];
            const float4 wb = wq[(size_t)(kh * 96 + k4 + 1) * 256];
            const float4 wc = wq[(size_t)(kh * 96 + k4 + 2) * 256];
            const float4 wd = wq[(size_t)(kh * 96 + k4 + 3) * 256];
            const float4 ca = c4[k4], cb = c4[k4 + 1], cx = c4[k4 + 2], cd = c4[k4 + 3];
            s0 = fmaf(wa.x, ca.x, s0); s0 = fmaf(wa.y, ca.y, s0);
            s0 = fmaf(wa.z, ca.z, s0); s0 = fmaf(wa.w, ca.w, s0);
            s1 = fmaf(wb.x, cb.x, s1); s1 = fmaf(wb.y, cb.y, s1);
            s1 = fmaf(wb.z, cb.z, s1); s1 = fmaf(wb.w, cb.w, s1);
            s2 = fmaf(wc.x, cx.x, s2); s2 = fmaf(wc.y, cx.y, s2);
            s2 = fmaf(wc.z, cx.z, s2); s2 = fmaf(wc.w, cx.w, s2);
            s3 = fmaf(wd.x, cd.x, s3); s3 = fmaf(wd.y, cd.y, s3);
            s3 = fmaf(wd.z, cd.z, s3); s3 = fmaf(wd.w, cd.w, s3);
        }
        part[g][o] = (s0 + s1) + (s2 + s3);
    }
    __syncthreads();
    if (t < 512) {
        const int c = t >> 8;
        pcat[256 + (c << 8) + o] = part[c][o] + part[c + 2][o] + bpar[o];
    } else if (t < 768) {
        const int idx = t & 255;
        pcat[idx] = embed[(size_t)values[i] * HID + idx];
    }
    __syncthreads();
    {
        const float4* wq = (const float4*)Wq + o;
        const float4* c4 = (const float4*)pcat + g * 48;
        float s0 = 0.f, s1 = 0.f, s2 = 0.f, s3 = 0.f;
#pragma unroll
        for (int k4 = 0; k4 < 48; k4 += 4) {
            const float4 wa = wq[(size_t)(g * 48 + k4) * 256];
            const float4 wb = wq[(size_t)(g * 48 + k4 + 1) * 256];
            const float4 wc = wq[(size_t)(g * 48 + k4 + 2) * 256];
            const float4 wd = wq[(size_t)(g * 48 + k4 + 3) * 256];
            const float4 ca = c4[k4], cb = c4[k4 + 1], cx = c4[k4 + 2], cd = c4[k4 + 3];
            s0 = fmaf(wa.x, ca.x, s0); s0 = fmaf(wa.y, ca.y, s0);
            s0 = fmaf(wa.z, ca.z, s0); s0 = fmaf(wa.w, ca.w, s0);
            s1 = fmaf(wb.x, cb.x, s1); s1 = fmaf(wb.y, cb.y, s1);
            s1 = fmaf(wb.z, cb.z, s1); s1 = fmaf(wb.w, cb.w, s1);
            s2 = fmaf(wc.x, cx.x, s2); s2 = fmaf(wc.y, cx.y, s2);
            s2 = fmaf(wc.z, cx.z, s2); s2 = fmaf(wc.w, cx.w, s2);
            s3 = fmaf(wd.x, cd.x, s3); s3 = fmaf(wd.y, cd.y, s3);
            s3 = fmaf(wd.z, cd.z, s3); s3 = fmaf(wd.w, cd.w, s3);
        }
        part[g][o] = (s0 + s1) + (s2 + s3);
    }
    __syncthreads();
    if (t < 256)
        h[(size_t)i * HID + t] = part[0][t] + part[1][t] + part[2][t] + part[3][t] + bpar[t];
}

// ---------------- persistent encoder tail: 6 levels, 1 launch ----------------
// 64 blocks x 256 threads, all co-resident. Normal cached loads/stores for h;
// cross-XCD coherence provided at the barrier only: release __threadfence()
// (buffer_wbl2: flush h-stores past the XCD L2) before arrive, RELAXED
// agent-scope spin (reads through to coherent point, no cache-invalidate storm),
// acquire __threadfence() (invalidate stale lines) after exit.
__device__ __forceinline__ void gridbar(int* bar, int nblk) {
    __syncthreads();
    if (threadIdx.x == 0) {
        __threadfence();               // release: h-stores visible device-wide
        const int gen = __hip_atomic_load(&bar[1], __ATOMIC_RELAXED,
                                          __HIP_MEMORY_SCOPE_AGENT);
        if (__hip_atomic_fetch_add(&bar[0], 1, __ATOMIC_RELAXED,
                                   __HIP_MEMORY_SCOPE_AGENT) == nblk - 1) {
            __hip_atomic_store(&bar[0], 0, __ATOMIC_RELAXED,
                               __HIP_MEMORY_SCOPE_AGENT);
            __hip_atomic_fetch_add(&bar[1], 1, __ATOMIC_RELAXED,
                                   __HIP_MEMORY_SCOPE_AGENT);
        } else {
            while (__hip_atomic_load(&bar[1], __ATOMIC_RELAXED,
                                     __HIP_MEMORY_SCOPE_AGENT) == gen) { }
        }
        __threadfence();               // acquire: drop stale L1/L2 lines
    }
    __syncthreads();
}

__global__ __launch_bounds__(256, 1)
void enc_persist(const float* __restrict__ embed, const int* __restrict__ values,
                 const float* __restrict__ Wq, const float* __restrict__ bpar,
                 float* h, int* bar) {
    const int t = threadIdx.x;
    __shared__ __align__(16) float cat_s[768];
    __shared__ float part_s[256];
    const int firsts[6] = {31, 15, 7, 3, 1, 0};

#pragma unroll 1
    for (int lvl = 0; lvl < 6; lvl++) {
        const int logS = lvl + 1;
        const int S = 1 << logS;
        const int R = 256 >> logS;
        const int node = firsts[lvl] + ((int)blockIdx.x >> logS);
        const int slice = (int)blockIdx.x & (S - 1);
        const int rl = t & (R - 1);
        const int g = t >> (8 - logS);

        // stage cat(node) with NORMAL cached loads (barrier provides coherence)
        for (int e = t; e < 768; e += 256) {
            const int seg = e >> 8, idx = e & 255;
            cat_s[e] = (seg == 0) ? embed[(size_t)values[node] * HID + idx]
                                  : h[(size_t)(2 * node + seg) * HID + idx];
        }
        __syncthreads();

        const int r0 = slice * R;
        const int nk4 = 192 >> logS;               // 96,48,24,12,6,3
        const float4* wq = (const float4*)Wq + (size_t)(g * nk4) * 256 + r0 + rl;
        const float4* c4 = (const float4*)cat_s + g * nk4;
        float s0 = 0.f, s1 = 0.f, s2 = 0.f, s3 = 0.f;
        if (nk4 >= 12) {
            for (int k4 = 0; k4 < nk4; k4 += 4) {
                const float4 wa = wq[(size_t)(k4) * 256];
                const float4 wb = wq[(size_t)(k4 + 1) * 256];
                const float4 wc = wq[(size_t)(k4 + 2) * 256];
                const float4 wd = wq[(size_t)(k4 + 3) * 256];
                const float4 ca = c4[k4], cb = c4[k4 + 1], cx = c4[k4 + 2], cd = c4[k4 + 3];
                s0 = fmaf(wa.x, ca.x, s0); s0 = fmaf(wa.y, ca.y, s0);
                s0 = fmaf(wa.z, ca.z, s0); s0 = fmaf(wa.w, ca.w, s0);
                s1 = fmaf(wb.x, cb.x, s1); s1 = fmaf(wb.y, cb.y, s1);
                s1 = fmaf(wb.z, cb.z, s1); s1 = fmaf(wb.w, cb.w, s1);
                s2 = fmaf(wc.x, cx.x, s2); s2 = fmaf(wc.y, cx.y, s2);
                s2 = fmaf(wc.z, cx.z, s2); s2 = fmaf(wc.w, cx.w, s2);
                s3 = fmaf(wd.x, cd.x, s3); s3 = fmaf(wd.y, cd.y, s3);
                s3 = fmaf(wd.z, cd.z, s3); s3 = fmaf(wd.w, cd.w, s3);
            }
        } else {
            for (int k4 = 0; k4 < nk4; k4++) {     // nk4 = 6 or 3
                const float4 wa = wq[(size_t)k4 * 256];
                const float4 ca = c4[k4];
                s0 = fmaf(wa.x, ca.x, s0); s1 = fmaf(wa.y, ca.y, s1);
                s2 = fmaf(wa.z, ca.z, s2); s3 = fmaf(wa.w, ca.w, s3);
            }
        }
        part_s[t] = (s0 + s1) + (s2 + s3);
        __syncthreads();
        if (t < R) {
            float v = bpar[r0 + t];
            for (int g2 = 0; g2 < S; g2++) v += part_s[g2 * R + t];
            h[(size_t)node * HID + r0 + t] = v;    // normal cached store
        }
        if (lvl < 5) gridbar(bar, 64);
        else __syncthreads();
    }
}

// ---------------- decoder recurrence + fused head ----------------------------
__global__ __launch_bounds__(512, 2)
void recur_kernel(const float* W1, const float* b1,
                  const float* W2, const float* b2,
                  const float* Wcomb, const float* bcomb,
                  const float* h0,
                  const float* Wq_mu, const float* bmu,
                  const float* Wq_lv, const float* blv,
                  const float* eps, float* out,
                  float* Hrec, int* rowflag) {
    const int t = threadIdx.x;
    const int o = t >> 1;                  // 0..255
    const int hk = t & 1;
    __shared__ __align__(16) float stack_s[64 * 128];   // 32 KB
    __shared__ __align__(16) float hmid_s[256];
    __shared__ float c0part_s[8];

    float4 w1r[16];
#pragma unroll
    for (int j = 0; j < 16; j++)
        w1r[j] = *(const float4*)(W1 + (size_t)o * 128 + hk * 64 + 4 * j);
    float4 wcr[32];
#pragma unroll
    for (int j = 0; j < 32; j++)
        wcr[j] = *(const float4*)(Wcomb + (size_t)o * 256 + hk * 128 + 4 * j);

    const float b1o = b1[o];
    const float bco = bcomb[o];
    const float b20 = b2[0];
    const float w2o = W2[o];               // W2 row 0, element o

    // ---- fused head: mu/lv from h0, z into stack slot 0 ----
    if (t < 256) hmid_s[t] = h0[t];
    __syncthreads();
    {
        const int r = o & 127;
        const float4* wqh = (const float4*)(o < 128 ? Wq_mu : Wq_lv) + r;
        const float4* r4 = (const float4*)hmid_s + hk * 32;
        float s0 = 0.f, s1 = 0.f;
#pragma unroll
        for (int k4 = 0; k4 < 32; k4 += 2) {
            const float4 wa = wqh[(size_t)(hk * 32 + k4) * 128];
            const float4 wb = wqh[(size_t)(hk * 32 + k4 + 1) * 128];
            const float4 ca = r4[k4], cb = r4[k4 + 1];
            s0 = fmaf(wa.x, ca.x, s0); s0 = fmaf(wa.y, ca.y, s0);
            s0 = fmaf(wa.z, ca.z, s0); s0 = fmaf(wa.w, ca.w, s0);
            s1 = fmaf(wb.x, cb.x, s1); s1 = fmaf(wb.y, cb.y, s1);
            s1 = fmaf(wb.z, cb.z, s1); s1 = fmaf(wb.w, cb.w, s1);
        }
        float a = s0 + s1;
        a += __shfl_xor(a, 1);
        if (hk == 0) {
            const float v = a + (o < 128 ? bmu[o & 127] : blv[o & 127]);
            out[(size_t)NSTEP * VOC + o] = v;
            stack_s[128 + o] = v;           // mu -> [128..255], lv -> [256..383]
        }
    }
    __syncthreads();
    if (t < 128)                             // z = mu + eps*exp(0.5*lv)
        stack_s[t] = stack_s[128 + t] + eps[t] * expf(0.5f * stack_s[256 + t]);

    int sp = 1, op = 0;
    unsigned long long pm0 = 0ULL, pm1 = 0ULL;
    __syncthreads();

    for (int step = 0; step < NSTEP; step++) {
        if (sp <= 0) break;
        const int idx = sp - 1;

        // mv1: hmid = lrelu(W1 @ node + b1), split-K=2 (even/odd lanes)
        const float* np = stack_s + idx * 128 + hk * 64;
        float a0 = 0.f, a1 = 0.f;
#pragma unroll
        for (int j = 0; j < 16; j += 2) {
            const float4 v0r = *(const float4*)(np + 4 * j);
            const float4 v1r = *(const float4*)(np + 4 * j + 4);
            a0 = fmaf(w1r[j].x, v0r.x, a0);     a0 = fmaf(w1r[j].y, v0r.y, a0);
            a0 = fmaf(w1r[j].z, v0r.z, a0);     a0 = fmaf(w1r[j].w, v0r.w, a0);
            a1 = fmaf(w1r[j + 1].x, v1r.x, a1); a1 = fmaf(w1r[j + 1].y, v1r.y, a1);
            a1 = fmaf(w1r[j + 1].z, v1r.z, a1); a1 = fmaf(w1r[j + 1].w, v1r.w, a1);
        }
        float a = a0 + a1;
        a += __shfl_xor(a, 1);                 // both lanes of pair hold full sum

        // activation on both lanes; per-wave c0 partial PRE-barrier
        float act = a + b1o;
        act = act > 0.f ? act : 0.2f * act;
        float m = w2o * act;                   // lanes 2o,2o+1 duplicate m_o
        m += __shfl_xor(m, 2);  m += __shfl_xor(m, 4);  m += __shfl_xor(m, 8);
        m += __shfl_xor(m, 16); m += __shfl_xor(m, 32);
        if ((t & 63) == 0) c0part_s[t >> 6] = m;
        if (hk == 0) {
            hmid_s[o] = act;
            Hrec[(size_t)op * HID + o] = act;   // remat-blocker + record
        }
        __syncthreads();                         // b1: hmid + c0 partials visible

        // c0 decision: 8 partials, broadcast read + adds (wave-uniform)
        const float4 q0 = ((const float4*)c0part_s)[0];
        const float4 q1 = ((const float4*)c0part_s)[1];
        const float c = ((q0.x + q0.y) + (q0.z + q0.w)) +
                        ((q1.x + q1.y) + (q1.z + q1.w)) + b20;
        const bool par = (c > 0.f) && (sp <= 63);

        if (par) {
            // mv2: push = Wcomb @ hmid + bcomb (parents only), 4 fmaf chains
            const float* hp = hmid_s + hk * 128;
            float s0 = 0.f, s1 = 0.f, s2 = 0.f, s3 = 0.f;
#pragma unroll
            for (int j = 0; j < 32; j += 4) {
                const float4 v0r = *(const float4*)(hp + 4 * j);
                const float4 v1r = *(const float4*)(hp + 4 * j + 4);
                const float4 v2r = *(const float4*)(hp + 4 * j + 8);
                const float4 v3r = *(const float4*)(hp + 4 * j + 12);
                s0 = fmaf(wcr[j].x, v0r.x, s0);     s0 = fmaf(wcr[j].y, v0r.y, s0);
                s0 = fmaf(wcr[j].z, v0r.z, s0);     s0 = fmaf(wcr[j].w, v0r.w, s0);
                s1 = fmaf(wcr[j + 1].x, v1r.x, s1); s1 = fmaf(wcr[j + 1].y, v1r.y, s1);
                s1 = fmaf(wcr[j + 1].z, v1r.z, s1); s1 = fmaf(wcr[j + 1].w, v1r.w, s1);
                s2 = fmaf(wcr[j + 2].x, v2r.x, s2); s2 = fmaf(wcr[j + 2].y, v2r.y, s2);
                s2 = fmaf(wcr[j + 2].z, v2r.z, s2); s2 = fmaf(wcr[j + 2].w, v2r.w, s2);
                s3 = fmaf(wcr[j + 3].x, v3r.x, s3); s3 = fmaf(wcr[j + 3].y, v3r.y, s3);
                s3 = fmaf(wcr[j + 3].z, v3r.z, s3); s3 = fmaf(wcr[j + 3].w, v3r.w, s3);
            }
            float s = (s0 + s1) + (s2 + s3);
            s += __shfl_xor(s, 1);
            if (hk == 0)                           // ll -> idx, rl -> idx+1
                stack_s[(idx + (o >> 7)) * 128 + (o & 127)] = s + bco;
            if (op < 64) pm0 |= (1ULL << op); else pm1 |= (1ULL << (op - 64));
            sp += 1;
        } else {
            sp -= 1;
        }
        op++;
        __syncthreads();                         // b2: stack update visible
    }

    if (t < 128) {
        int f = -1;
        if (t < op) f = (t < 64) ? (int)((pm0 >> t) & 1) : (int)((pm1 >> (t - 64)) & 1);
        rowflag[t] = f;
    }
}

// ---------------- Co1 = Hrec @ W2[1:].T + b2[1:] + free list-compaction ------
__global__ __launch_bounds__(256)
void co1_kernel(const float* __restrict__ Hrec, const float* __restrict__ Wq_w2,
                const float* __restrict__ b2, const int* __restrict__ rowflag,
                float* __restrict__ Co1, int* __restrict__ lists) {
    const int r = blockIdx.x;              // 0..127 matvec rows, 128 = scan
    const int c = threadIdx.x;             // 0..255
    if (r == 128) {
        if (c == 0) {
            int nl = 0, np_ = 0, nz = 0;
            for (int q = 0; q < 128; q++) {
                const int f = rowflag[q];
                if (f == 0) lists[nl++] = q;
                else if (f == 1) lists[128 + np_++] = q;
                else lists[256 + nz++] = q;
            }
            lists[384] = nl; lists[385] = np_; lists[386] = nz;
        }
        return;
    }
    __shared__ __align__(16) float hs[256];
    hs[c] = Hrec[(size_t)r * HID + c];
    __syncthreads();
    const float4* wq = (const float4*)Wq_w2 + c;
    const float4* h4 = (const float4*)hs;
    float s0 = b2[1 + c], s1 = 0.f, s2 = 0.f, s3 = 0.f;
#pragma unroll 8
    for (int k4 = 0; k4 < 64; k4 += 4) {
        const float4 a0 = wq[(k4) * 256],     h0 = h4[k4];
        const float4 a1 = wq[(k4 + 1) * 256], h1 = h4[k4 + 1];
        const float4 a2 = wq[(k4 + 2) * 256], h2 = h4[k4 + 2];
        const float4 a3 = wq[(k4 + 3) * 256], h3 = h4[k4 + 3];
        s0 = fmaf(a0.x, h0.x, s0); s0 = fmaf(a0.y, h0.y, s0);
        s0 = fmaf(a0.z, h0.z, s0); s0 = fmaf(a0.w, h0.w, s0);
        s1 = fmaf(a1.x, h1.x, s1); s1 = fmaf(a1.y, h1.y, s1);
        s1 = fmaf(a1.z, h1.z, s1); s1 = fmaf(a1.w, h1.w, s1);
        s2 = fmaf(a2.x, h2.x, s2); s2 = fmaf(a2.y, h2.y, s2);
        s2 = fmaf(a2.z, h2.z, s2); s2 = fmaf(a2.w, h2.w, s2);
        s3 = fmaf(a3.x, h3.x, s3); s3 = fmaf(a3.y, h3.y, s3);
        s3 = fmaf(a3.z, h3.z, s3); s3 = fmaf(a3.w, h3.w, s3);
    }
    Co1[(size_t)r * HID + c] = (s0 + s1) + (s2 + s3);
}

// ---------------- batched vocab matvecs --------------------------------------
__global__ __launch_bounds__(256, 2)
void value_kernel(const float* __restrict__ Co1, const int* __restrict__ lists,
                  const float* __restrict__ Wl, const float* __restrict__ bl,
                  const float* __restrict__ Wp, const float* __restrict__ bp,
                  float* __restrict__ out) {
    const int m = blockIdx.y;              // 0 = leaf (Wl) + zero rows, 1 = parent (Wp)
    const int t = threadIdx.x;
    const int v = blockIdx.x * 128 + (t & 127);   // 250 blocks x 128 = 32000
    const int rh = t >> 7;                 // row-parity half (uniform per wave)
    const int n = lists[384 + m];
    const int* list = lists + m * 128;
    const float* Wx = m ? Wp : Wl;
    const float* bx = m ? bp : bl;
    const float bv = bx[v];
    const float4* w4 = (const float4*)(Wx + (size_t)v * HID);

    for (int rc = 0; rc < n; rc += 32) {
        const int nr = min(32, n - rc);
        float acc[16];
#pragma unroll
        for (int i = 0; i < 16; i++) acc[i] = 0.f;
        for (int kc = 0; kc < 4; kc++) {
            float4 w[16];
#pragma unroll
            for (int i = 0; i < 16; i++) w[i] = w4[kc * 16 + i];
#pragma unroll
            for (int aa = 0; aa < 16; aa++) {
                const int rr = 2 * aa + rh;
                if (rr < nr) {
                    const int row = __builtin_amdgcn_readfirstlane(list[rc + rr]);
                    const float* cp = Co1 + (size_t)row * HID + kc * 64;
                    float s0 = 0.f, s1 = 0.f, s2 = 0.f, s3 = 0.f;
#pragma unroll
                    for (int i = 0; i < 16; i += 4) {
                        const float4 c0 = *(const float4*)(cp + 4 * i);
                        const float4 c1 = *(const float4*)(cp + 4 * i + 4);
                        const float4 c2 = *(const float4*)(cp + 4 * i + 8);
                        const float4 c3 = *(const float4*)(cp + 4 * i + 12);
                        s0 = fmaf(w[i].x, c0.x, s0);     s0 = fmaf(w[i].y, c0.y, s0);
                        s0 = fmaf(w[i].z, c0.z, s0);     s0 = fmaf(w[i].w, c0.w, s0);
                        s1 = fmaf(w[i + 1].x, c1.x, s1); s1 = fmaf(w[i + 1].y, c1.y, s1);
                        s1 = fmaf(w[i + 1].z, c1.z, s1); s1 = fmaf(w[i + 1].w, c1.w, s1);
                        s2 = fmaf(w[i + 2].x, c2.x, s2); s2 = fmaf(w[i + 2].y, c2.y, s2);
                        s2 = fmaf(w[i + 2].z, c2.z, s2); s2 = fmaf(w[i + 2].w, c2.w, s2);
                        s3 = fmaf(w[i + 3].x, c3.x, s3); s3 = fmaf(w[i + 3].y, c3.y, s3);
                        s3 = fmaf(w[i + 3].z, c3.z, s3); s3 = fmaf(w[i + 3].w, c3.w, s3);
                    }
                    acc[aa] += (s0 + s1) + (s2 + s3);
                }
            }
        }
#pragma unroll
        for (int aa = 0; aa < 16; aa++) {
            const int rr = 2 * aa + rh;
            if (rr < nr) {
                const int row = __builtin_amdgcn_readfirstlane(list[rc + rr]);
                out[(size_t)row * VOC + v] = acc[aa] + bv;
            }
        }
    }
    if (m == 0 && rh == 0) {
        const int nz = lists[386];
        const int* zl = lists + 256;
        for (int i = 0; i < nz; i++)
            out[(size_t)zl[i] * VOC + v] = 0.f;
    }
}

extern "C" void kernel_launch(void* const* d_in, const int* in_sizes, int n_in,
                              void* d_out, int out_size, void* d_ws, size_t ws_size,
                              hipStream_t stream) {
    const float* embed = (const float*)d_in[0];
    const float* Wpar  = (const float*)d_in[1];
    const float* bpar  = (const float*)d_in[2];
    const float* Wmu   = (const float*)d_in[3];
    const float* bmu   = (const float*)d_in[4];
    const float* Wlv   = (const float*)d_in[5];
    const float* blv   = (const float*)d_in[6];
    const float* W1    = (const float*)d_in[7];
    const float* b1    = (const float*)d_in[8];
    const float* W2    = (const float*)d_in[9];
    const float* b2    = (const float*)d_in[10];
    const float* Wl    = (const float*)d_in[11];
    const float* bl    = (const float*)d_in[12];
    const float* Wp    = (const float*)d_in[13];
    const float* bp    = (const float*)d_in[14];
    const float* eps   = (const float*)d_in[15];
    const int*  values = (const int*)d_in[16];

    float* ws = (float*)d_ws;
    float* h       = ws;                    // 255*256 = 65280
    float* Wcomb   = ws + 65408;            // 65536
    float* bcomb   = ws + 130944;           // 256
    float* Hrec    = ws + 131200;           // 32768
    float* Co1     = ws + 163968;           // 32768
    int*   rowflag = (int*)(ws + 196736);   // 128
    float* Wq_par  = ws + 196864;           // 196608
    float* Wq_mu   = ws + 393472;           // 32768
    float* Wq_lv   = ws + 426240;           // 32768
    float* Wq_w2   = ws + 459008;           // 65536
    int*   lists   = (int*)(ws + 524544);   // 387 ints
    int*   bar     = (int*)(ws + 524960);   // 2 ints (grid barrier)
    float* out = (float*)d_out;

    // prep: wcomb (256) + Wpar pack (96) + mu/lv pack (32) + W2 pack (32)
    prep_kernel<<<416, 512, 0, stream>>>(Wp, W2, b2, bp, Wpar, Wmu, Wlv,
                                         Wcomb, bcomb, Wq_par, Wq_mu, Wq_lv, Wq_w2,
                                         bar);

    // encoder: levels 8+7 fused (64 blocks), then persistent 6-level tail
    enc2<<<64, 1024, 0, stream>>>(embed, values, Wq_par, bpar, h, 63);
    enc_persist<<<64, 256, 0, stream>>>(embed, values, Wq_par, bpar, h, bar);

    // decoder recurrence with fused head
    recur_kernel<<<1, 512, 0, stream>>>(W1, b1, W2, b2, Wcomb, bcomb, h,
                                        Wq_mu, bmu, Wq_lv, blv, eps, out,
                                        Hrec, rowflag);

    co1_kernel<<<129, 256, 0, stream>>>(Hrec, Wq_w2, b2, rowflag, Co1, lists);
    value_kernel<<<dim3(250, 2), 256, 0, stream>>>(Co1, lists, Wl, bl, Wp, bp, out);
}

// Round 9
// 242.525 us; speedup vs baseline: 1.1517x; 1.1517x over previous
//
#include <hip/hip_runtime.h>

#define HID 256
#define LAT 128
#define VOC 32000
#define NSTEP 128

// ---------------- prep: wcomb (split-j) + block-transposed weight packs ------
// Wq layouts: Wq[k4*R + r] (float4) = W[r][4k4..4k4+3]  -> thread-per-row
// matvecs get lane-consecutive (coalesced) weight loads.
__global__ __launch_bounds__(512)
void prep_kernel(const float* __restrict__ Wp, const float* __restrict__ W2,
                 const float* __restrict__ b2, const float* __restrict__ bp,
                 const float* __restrict__ Wpar,
                 const float* __restrict__ Wmu, const float* __restrict__ Wlv,
                 float* __restrict__ Wcomb, float* __restrict__ bcomb,
                 float* __restrict__ Wq_par, float* __restrict__ Wq_mu,
                 float* __restrict__ Wq_lv, float* __restrict__ Wq_w2) {
    const int b = blockIdx.x;
    const int t = threadIdx.x;
    if (b < 256) {                     // Wcomb row o = Wp_tail[o] @ W2[1:], bcomb[o]
        const int o = b;
        const int k = t & 255, jh = t >> 8;
        __shared__ float wpt_s[256];
        __shared__ float part_s[2][256];
        __shared__ float red_s[4];
        if (t < 256) wpt_s[t] = Wp[(size_t)(VOC + o) * HID + t];
        __syncthreads();
        float acc = 0.f;
#pragma unroll 8
        for (int j = 0; j < 128; j++)
            acc += wpt_s[jh * 128 + j] * W2[(size_t)(1 + jh * 128 + j) * HID + k];
        part_s[jh][k] = acc;
        if (t < 256) {
            float p = wpt_s[k] * b2[1 + k];
            p += __shfl_xor(p, 1);  p += __shfl_xor(p, 2);  p += __shfl_xor(p, 4);
            p += __shfl_xor(p, 8);  p += __shfl_xor(p, 16); p += __shfl_xor(p, 32);
            if ((k & 63) == 0) red_s[k >> 6] = p;
        }
        __syncthreads();
        if (t < 256) Wcomb[(size_t)o * HID + k] = part_s[0][k] + part_s[1][k];
        if (t == 0) bcomb[o] = bp[VOC + o] + red_s[0] + red_s[1] + red_s[2] + red_s[3];
    } else if (b < 352) {              // Wpar pack: 96 blocks x 2 k4
        const int k4 = (b - 256) * 2 + (t >> 8);
        const int r = t & 255;
        ((float4*)Wq_par)[k4 * 256 + r] = *(const float4*)(Wpar + (size_t)r * 768 + 4 * k4);
    } else if (b < 384) {              // Wmu/Wlv pack: 32 blocks x 2 k4
        const int k4 = (b - 352) * 2 + (t >> 8);
        const int r = t & 127, sel = (t >> 7) & 1;
        const float* src = (sel ? Wlv : Wmu) + (size_t)r * HID + 4 * k4;
        ((float4*)(sel ? Wq_lv : Wq_mu))[k4 * 128 + r] = *(const float4*)src;
    } else {                           // W2[1:] pack: 32 blocks x 2 k4
        const int k4 = (b - 384) * 2 + (t >> 8);
        const int r = t & 255;
        ((float4*)Wq_w2)[k4 * 256 + r] = *(const float4*)(W2 + (size_t)(1 + r) * HID + 4 * k4);
    }
}

// ---------------- fused two-level encoder (levels 8+7 -> h[63..126]) ---------
__global__ __launch_bounds__(1024)
void enc2(const float* __restrict__ embed, const int* __restrict__ values,
          const float* __restrict__ Wq, const float* __restrict__ bpar,
          float* __restrict__ h, int base) {
    const int i = base + blockIdx.x;
    const int t = threadIdx.x;
    const int o = t & 255;
    const int g = t >> 8;              // 0..3
    const int cid = g & 1, kh = g >> 1;
    __shared__ __align__(16) float cat[2][768];
    __shared__ float part[4][256];
    __shared__ __align__(16) float pcat[768];

    const int c0n = 2 * i + 1;
    for (int q = t; q < 1536; q += 1024) {
        const int cc = (q >= 768);
        const int e = q - cc * 768;
        const int node = c0n + cc;
        const int seg = e >> 8, idx = e & 255;
        float v;
        if (seg == 0) v = embed[(size_t)values[node] * HID + idx];
        else {
            const int ch = 2 * node + seg;     // seg=1 -> 2n+1, seg=2 -> 2n+2
            v = (ch >= 255) ? embed[(size_t)values[ch] * HID + idx]
                            : h[(size_t)ch * HID + idx];
        }
        cat[cc][e] = v;
    }
    __syncthreads();
    // phase 1: child matvecs (parallel children, split-K=2)
    {
        const float4* wq = (const float4*)Wq + o;
        const float4* c4 = (const float4*)cat[cid] + kh * 96;
        float s0 = 0.f, s1 = 0.f, s2 = 0.f, s3 = 0.f;
#pragma unroll 8
        for (int k4 = 0; k4 < 96; k4 += 4) {
            const float4 wa = wq[(size_t)(kh * 96 + k4) * 256];
            const float4 wb = wq[(size_t)(kh * 96 + k4 + 1) * 256];
            const float4 wc = wq[(size_t)(kh * 96 + k4 + 2) * 256];
            const float4 wd = wq[(size_t)(kh * 96 + k4 + 3) * 256];
            const float4 ca = c4[k4], cb = c4[k4 + 1], cx = c4[k4 + 2], cd = c4[k4 + 3];
            s0 = fmaf(wa.x, ca.x, s0); s0 = fmaf(wa.y, ca.y, s0);
            s0 = fmaf(wa.z, ca.z, s0); s0 = fmaf(wa.w, ca.w, s0);
            s1 = fmaf(wb.x, cb.x, s1); s1 = fmaf(wb.y, cb.y, s1);
            s1 = fmaf(wb.z, cb.z, s1); s1 = fmaf(wb.w, cb.w, s1);
            s2 = fmaf(wc.x, cx.x, s2); s2 = fmaf(wc.y, cx.y, s2);
            s2 = fmaf(wc.z, cx.z, s2); s2 = fmaf(wc.w, cx.w, s2);
            s3 = fmaf(wd.x, cd.x, s3); s3 = fmaf(wd.y, cd.y, s3);
            s3 = fmaf(wd.z, cd.z, s3); s3 = fmaf(wd.w, cd.w, s3);
        }
        part[g][o] = (s0 + s1) + (s2 + s3);
    }
    __syncthreads();
    // combine children + stage parent cat (one barrier)
    if (t < 512) {
        const int c = t >> 8;
        pcat[256 + (c << 8) + o] = part[c][o] + part[c + 2][o] + bpar[o];
    } else if (t < 768) {
        const int idx = t & 255;
        pcat[idx] = embed[(size_t)values[i] * HID + idx];
    }
    __syncthreads();
    // phase 2: parent matvec, split-K=4
    {
        const float4* wq = (const float4*)Wq + o;
        const float4* c4 = (const float4*)pcat + g * 48;
        float s0 = 0.f, s1 = 0.f, s2 = 0.f, s3 = 0.f;
#pragma unroll
        for (int k4 = 0; k4 < 48; k4 += 4) {
            const float4 wa = wq[(size_t)(g * 48 + k4) * 256];
            const float4 wb = wq[(size_t)(g * 48 + k4 + 1) * 256];
            const float4 wc = wq[(size_t)(g * 48 + k4 + 2) * 256];
            const float4 wd = wq[(size_t)(g * 48 + k4 + 3) * 256];
            const float4 ca = c4[k4], cb = c4[k4 + 1], cx = c4[k4 + 2], cd = c4[k4 + 3];
            s0 = fmaf(wa.x, ca.x, s0); s0 = fmaf(wa.y, ca.y, s0);
            s0 = fmaf(wa.z, ca.z, s0); s0 = fmaf(wa.w, ca.w, s0);
            s1 = fmaf(wb.x, cb.x, s1); s1 = fmaf(wb.y, cb.y, s1);
            s1 = fmaf(wb.z, cb.z, s1); s1 = fmaf(wb.w, cb.w, s1);
            s2 = fmaf(wc.x, cx.x, s2); s2 = fmaf(wc.y, cx.y, s2);
            s2 = fmaf(wc.z, cx.z, s2); s2 = fmaf(wc.w, cx.w, s2);
            s3 = fmaf(wd.x, cd.x, s3); s3 = fmaf(wd.y, cd.y, s3);
            s3 = fmaf(wd.z, cd.z, s3); s3 = fmaf(wd.w, cd.w, s3);
        }
        part[g][o] = (s0 + s1) + (s2 + s3);
    }
    __syncthreads();
    if (t < 256)
        h[(size_t)i * HID + t] = part[0][t] + part[1][t] + part[2][t] + part[3][t] + bpar[t];
}

// ---------------- level kernel: node x output-slice blocks -------------------
// Each block computes R = 256>>logS output rows of ONE node's matvec, with
// split-K = S = 1<<logS among thread groups. Per-block weight traffic is
// 768*R*4 B, so small levels get S-fold more blocks pulling from L2 in
// parallel (traffic constant, bandwidth xS).
__global__ __launch_bounds__(256)
void enc_lvl(const float* __restrict__ embed, const int* __restrict__ values,
             const float* __restrict__ Wq, const float* __restrict__ bpar,
             float* __restrict__ h, int first, int logS) {
    const int S = 1 << logS;
    const int R = 256 >> logS;
    const int node = first + (blockIdx.x >> logS);
    const int slice = blockIdx.x & (S - 1);
    const int t = threadIdx.x;
    const int rl = t & (R - 1);
    const int g = t >> (8 - logS);
    __shared__ __align__(16) float cat_s[768];
    __shared__ float part_s[256];

    // stage cat(node) = [embed[values[node]] | h[2n+1] | h[2n+2]]
    for (int e = t; e < 768; e += 256) {
        const int seg = e >> 8, idx = e & 255;
        cat_s[e] = (seg == 0) ? embed[(size_t)values[node] * HID + idx]
                              : h[(size_t)(2 * node + seg) * HID + idx];
    }
    __syncthreads();

    const int r0 = slice * R;
    const int nk4 = 192 >> logS;                         // f4 per thread (96/48/24/12)
    const float4* wq = (const float4*)Wq + (size_t)(g * nk4) * 256 + r0 + rl;
    const float4* c4 = (const float4*)cat_s + g * nk4;
    float s0 = 0.f, s1 = 0.f, s2 = 0.f, s3 = 0.f;
    for (int k4 = 0; k4 < nk4; k4 += 4) {
        const float4 wa = wq[(size_t)(k4) * 256];
        const float4 wb = wq[(size_t)(k4 + 1) * 256];
        const float4 wc = wq[(size_t)(k4 + 2) * 256];
        const float4 wd = wq[(size_t)(k4 + 3) * 256];
        const float4 ca = c4[k4], cb = c4[k4 + 1], cx = c4[k4 + 2], cd = c4[k4 + 3];
        s0 = fmaf(wa.x, ca.x, s0); s0 = fmaf(wa.y, ca.y, s0);
        s0 = fmaf(wa.z, ca.z, s0); s0 = fmaf(wa.w, ca.w, s0);
        s1 = fmaf(wb.x, cb.x, s1); s1 = fmaf(wb.y, cb.y, s1);
        s1 = fmaf(wb.z, cb.z, s1); s1 = fmaf(wb.w, cb.w, s1);
        s2 = fmaf(wc.x, cx.x, s2); s2 = fmaf(wc.y, cx.y, s2);
        s2 = fmaf(wc.z, cx.z, s2); s2 = fmaf(wc.w, cx.w, s2);
        s3 = fmaf(wd.x, cd.x, s3); s3 = fmaf(wd.y, cd.y, s3);
        s3 = fmaf(wd.z, cd.z, s3); s3 = fmaf(wd.w, cd.w, s3);
    }
    part_s[t] = (s0 + s1) + (s2 + s3);
    __syncthreads();
    if (t < R) {
        float v = bpar[r0 + t];
        for (int g2 = 0; g2 < S; g2++) v += part_s[g2 * R + t];
        h[(size_t)node * HID + r0 + t] = v;
    }
}

// ---------------- sequential decoder recurrence + fused head -----------------
// Prologue computes mu/lv/z from h[0]. Main loop: mv1 -> c0 tree ->
// if(par){mv2+commit}. mv2 is wave-uniform-conditional, so leaf steps skip
// its issue cycles entirely.
__global__ __launch_bounds__(512, 2)
void recur_kernel(const float* W1, const float* b1,
                  const float* W2, const float* b2,
                  const float* Wcomb, const float* bcomb,
                  const float* h0,
                  const float* Wq_mu, const float* bmu,
                  const float* Wq_lv, const float* blv,
                  const float* eps, float* out,
                  float* Hrec, int* rowflag) {
    const int t = threadIdx.x;
    const int o = t >> 1;                  // 0..255
    const int hk = t & 1;
    __shared__ __align__(16) float stack_s[64 * 128];   // 32 KB
    __shared__ __align__(16) float hmid_s[256];

    float4 w1r[16];
#pragma unroll
    for (int j = 0; j < 16; j++)
        w1r[j] = *(const float4*)(W1 + (size_t)o * 128 + hk * 64 + 4 * j);
    float4 wcr[32];
#pragma unroll
    for (int j = 0; j < 32; j++)
        wcr[j] = *(const float4*)(Wcomb + (size_t)o * 256 + hk * 128 + 4 * j);

    const float b1o = b1[o];
    const float bco = bcomb[o];
    const float b20 = b2[0];
    const int l64 = t & 63;
    const float4 w2q = *(const float4*)(W2 + 4 * l64);

    // ---- fused head: mu/lv from h0, z into stack slot 0 ----
    if (t < 256) hmid_s[t] = h0[t];
    __syncthreads();
    {
        const int r = o & 127;              // virtual head row: o<128 mu, else lv
        const float4* wqh = (const float4*)(o < 128 ? Wq_mu : Wq_lv) + r;
        const float4* r4 = (const float4*)hmid_s + hk * 32;
        float s0 = 0.f, s1 = 0.f;
#pragma unroll
        for (int k4 = 0; k4 < 32; k4 += 2) {
            const float4 wa = wqh[(size_t)(hk * 32 + k4) * 128];
            const float4 wb = wqh[(size_t)(hk * 32 + k4 + 1) * 128];
            const float4 ca = r4[k4], cb = r4[k4 + 1];
            s0 = fmaf(wa.x, ca.x, s0); s0 = fmaf(wa.y, ca.y, s0);
            s0 = fmaf(wa.z, ca.z, s0); s0 = fmaf(wa.w, ca.w, s0);
            s1 = fmaf(wb.x, cb.x, s1); s1 = fmaf(wb.y, cb.y, s1);
            s1 = fmaf(wb.z, cb.z, s1); s1 = fmaf(wb.w, cb.w, s1);
        }
        float a = s0 + s1;
        a += __shfl_xor(a, 1);
        if (hk == 0) {
            const float v = a + (o < 128 ? bmu[o & 127] : blv[o & 127]);
            out[(size_t)NSTEP * VOC + o] = v;
            stack_s[128 + o] = v;           // mu -> [128..255], lv -> [256..383]
        }
    }
    __syncthreads();
    if (t < 128)                             // z = mu + eps*exp(0.5*lv)
        stack_s[t] = stack_s[128 + t] + eps[t] * expf(0.5f * stack_s[256 + t]);

    int sp = 1, op = 0;
    unsigned long long pm0 = 0ULL, pm1 = 0ULL;
    __syncthreads();

    for (int step = 0; step < NSTEP; step++) {
        if (sp <= 0) break;
        const int idx = sp - 1;

        // mv1: hmid = lrelu(W1 @ node + b1), split-K=2 (even/odd lanes)
        const float* np = stack_s + idx * 128 + hk * 64;
        float a0 = 0.f, a1 = 0.f;
#pragma unroll
        for (int j = 0; j < 16; j += 2) {
            const float4 v0r = *(const float4*)(np + 4 * j);
            const float4 v1r = *(const float4*)(np + 4 * j + 4);
            a0 = fmaf(w1r[j].x, v0r.x, a0);     a0 = fmaf(w1r[j].y, v0r.y, a0);
            a0 = fmaf(w1r[j].z, v0r.z, a0);     a0 = fmaf(w1r[j].w, v0r.w, a0);
            a1 = fmaf(w1r[j + 1].x, v1r.x, a1); a1 = fmaf(w1r[j + 1].y, v1r.y, a1);
            a1 = fmaf(w1r[j + 1].z, v1r.z, a1); a1 = fmaf(w1r[j + 1].w, v1r.w, a1);
        }
        float a = a0 + a1;
        a += __shfl_xor(a, 1);
        if (hk == 0) {
            float pre = a + b1o;
            pre = pre > 0.f ? pre : 0.2f * pre;
            hmid_s[o] = pre;
            Hrec[(size_t)op * HID + o] = pre;   // remat-blocker + record
        }
        __syncthreads();                         // b1: hmid visible

        // c0 decision dot: every wave redundantly (identical result)
        const float4 hq = *(const float4*)(hmid_s + 4 * l64);
        float c = w2q.x * hq.x + w2q.y * hq.y + w2q.z * hq.z + w2q.w * hq.w;
        c += __shfl_xor(c, 1);  c += __shfl_xor(c, 2);  c += __shfl_xor(c, 4);
        c += __shfl_xor(c, 8);  c += __shfl_xor(c, 16); c += __shfl_xor(c, 32);
        const bool par = ((c + b20) > 0.f) && (sp <= 63);

        if (par) {
            // mv2: push = Wcomb @ hmid + bcomb (parents only), 4 fmaf chains
            const float* hp = hmid_s + hk * 128;
            float s0 = 0.f, s1 = 0.f, s2 = 0.f, s3 = 0.f;
#pragma unroll
            for (int j = 0; j < 32; j += 4) {
                const float4 v0r = *(const float4*)(hp + 4 * j);
                const float4 v1r = *(const float4*)(hp + 4 * j + 4);
                const float4 v2r = *(const float4*)(hp + 4 * j + 8);
                const float4 v3r = *(const float4*)(hp + 4 * j + 12);
                s0 = fmaf(wcr[j].x, v0r.x, s0);     s0 = fmaf(wcr[j].y, v0r.y, s0);
                s0 = fmaf(wcr[j].z, v0r.z, s0);     s0 = fmaf(wcr[j].w, v0r.w, s0);
                s1 = fmaf(wcr[j + 1].x, v1r.x, s1); s1 = fmaf(wcr[j + 1].y, v1r.y, s1);
                s1 = fmaf(wcr[j + 1].z, v1r.z, s1); s1 = fmaf(wcr[j + 1].w, v1r.w, s1);
                s2 = fmaf(wcr[j + 2].x, v2r.x, s2); s2 = fmaf(wcr[j + 2].y, v2r.y, s2);
                s2 = fmaf(wcr[j + 2].z, v2r.z, s2); s2 = fmaf(wcr[j + 2].w, v2r.w, s2);
                s3 = fmaf(wcr[j + 3].x, v3r.x, s3); s3 = fmaf(wcr[j + 3].y, v3r.y, s3);
                s3 = fmaf(wcr[j + 3].z, v3r.z, s3); s3 = fmaf(wcr[j + 3].w, v3r.w, s3);
            }
            float s = (s0 + s1) + (s2 + s3);
            s += __shfl_xor(s, 1);
            if (hk == 0)                           // ll -> idx, rl -> idx+1
                stack_s[(idx + (o >> 7)) * 128 + (o & 127)] = s + bco;
            if (op < 64) pm0 |= (1ULL << op); else pm1 |= (1ULL << (op - 64));
            sp += 1;
        } else {
            sp -= 1;
        }
        op++;
        __syncthreads();                         // b2: stack update visible
    }

    if (t < 128) {
        int f = -1;
        if (t < op) f = (t < 64) ? (int)((pm0 >> t) & 1) : (int)((pm1 >> (t - 64)) & 1);
        rowflag[t] = f;
    }
}

// ---------------- Co1 = Hrec @ W2[1:].T + b2[1:] + free list-compaction ------
__global__ __launch_bounds__(256)
void co1_kernel(const float* __restrict__ Hrec, const float* __restrict__ Wq_w2,
                const float* __restrict__ b2, const int* __restrict__ rowflag,
                float* __restrict__ Co1, int* __restrict__ lists) {
    const int r = blockIdx.x;              // 0..127 matvec rows, 128 = scan
    const int c = threadIdx.x;             // 0..255
    if (r == 128) {
        if (c == 0) {
            int nl = 0, np_ = 0, nz = 0;
            for (int q = 0; q < 128; q++) {
                const int f = rowflag[q];
                if (f == 0) lists[nl++] = q;
                else if (f == 1) lists[128 + np_++] = q;
                else lists[256 + nz++] = q;
            }
            lists[384] = nl; lists[385] = np_; lists[386] = nz;
        }
        return;
    }
    __shared__ __align__(16) float hs[256];
    hs[c] = Hrec[(size_t)r * HID + c];
    __syncthreads();
    const float4* wq = (const float4*)Wq_w2 + c;
    const float4* h4 = (const float4*)hs;
    float s0 = b2[1 + c], s1 = 0.f, s2 = 0.f, s3 = 0.f;
#pragma unroll 8
    for (int k4 = 0; k4 < 64; k4 += 4) {
        const float4 a0 = wq[(k4) * 256],     h0 = h4[k4];
        const float4 a1 = wq[(k4 + 1) * 256], h1 = h4[k4 + 1];
        const float4 a2 = wq[(k4 + 2) * 256], h2 = h4[k4 + 2];
        const float4 a3 = wq[(k4 + 3) * 256], h3 = h4[k4 + 3];
        s0 = fmaf(a0.x, h0.x, s0); s0 = fmaf(a0.y, h0.y, s0);
        s0 = fmaf(a0.z, h0.z, s0); s0 = fmaf(a0.w, h0.w, s0);
        s1 = fmaf(a1.x, h1.x, s1); s1 = fmaf(a1.y, h1.y, s1);
        s1 = fmaf(a1.z, h1.z, s1); s1 = fmaf(a1.w, h1.w, s1);
        s2 = fmaf(a2.x, h2.x, s2); s2 = fmaf(a2.y, h2.y, s2);
        s2 = fmaf(a2.z, h2.z, s2); s2 = fmaf(a2.w, h2.w, s2);
        s3 = fmaf(a3.x, h3.x, s3); s3 = fmaf(a3.y, h3.y, s3);
        s3 = fmaf(a3.z, h3.z, s3); s3 = fmaf(a3.w, h3.w, s3);
    }
    Co1[(size_t)r * HID + c] = (s0 + s1) + (s2 + s3);
}

// ---------------- batched vocab matvecs --------------------------------------
__global__ __launch_bounds__(256, 2)
void value_kernel(const float* __restrict__ Co1, const int* __restrict__ lists,
                  const float* __restrict__ Wl, const float* __restrict__ bl,
                  const float* __restrict__ Wp, const float* __restrict__ bp,
                  float* __restrict__ out) {
    const int m = blockIdx.y;              // 0 = leaf (Wl) + zero rows, 1 = parent (Wp)
    const int t = threadIdx.x;
    const int v = blockIdx.x * 128 + (t & 127);   // 250 blocks x 128 = 32000
    const int rh = t >> 7;                 // row-parity half (uniform per wave)
    const int n = lists[384 + m];
    const int* list = lists + m * 128;
    const float* Wx = m ? Wp : Wl;
    const float* bx = m ? bp : bl;
    const float bv = bx[v];
    const float4* w4 = (const float4*)(Wx + (size_t)v * HID);

    for (int rc = 0; rc < n; rc += 32) {
        const int nr = min(32, n - rc);
        float acc[16];
#pragma unroll
        for (int i = 0; i < 16; i++) acc[i] = 0.f;
        for (int kc = 0; kc < 4; kc++) {
            float4 w[16];
#pragma unroll
            for (int i = 0; i < 16; i++) w[i] = w4[kc * 16 + i];
#pragma unroll
            for (int aa = 0; aa < 16; aa++) {
                const int rr = 2 * aa + rh;
                if (rr < nr) {
                    const int row = __builtin_amdgcn_readfirstlane(list[rc + rr]);
                    const float* cp = Co1 + (size_t)row * HID + kc * 64;
                    float s0 = 0.f, s1 = 0.f, s2 = 0.f, s3 = 0.f;
#pragma unroll
                    for (int i = 0; i < 16; i += 4) {
                        const float4 c0 = *(const float4*)(cp + 4 * i);
                        const float4 c1 = *(const float4*)(cp + 4 * i + 4);
                        const float4 c2 = *(const float4*)(cp + 4 * i + 8);
                        const float4 c3 = *(const float4*)(cp + 4 * i + 12);
                        s0 = fmaf(w[i].x, c0.x, s0);     s0 = fmaf(w[i].y, c0.y, s0);
                        s0 = fmaf(w[i].z, c0.z, s0);     s0 = fmaf(w[i].w, c0.w, s0);
                        s1 = fmaf(w[i + 1].x, c1.x, s1); s1 = fmaf(w[i + 1].y, c1.y, s1);
                        s1 = fmaf(w[i + 1].z, c1.z, s1); s1 = fmaf(w[i + 1].w, c1.w, s1);
                        s2 = fmaf(w[i + 2].x, c2.x, s2); s2 = fmaf(w[i + 2].y, c2.y, s2);
                        s2 = fmaf(w[i + 2].z, c2.z, s2); s2 = fmaf(w[i + 2].w, c2.w, s2);
                        s3 = fmaf(w[i + 3].x, c3.x, s3); s3 = fmaf(w[i + 3].y, c3.y, s3);
                        s3 = fmaf(w[i + 3].z, c3.z, s3); s3 = fmaf(w[i + 3].w, c3.w, s3);
                    }
                    acc[aa] += (s0 + s1) + (s2 + s3);
                }
            }
        }
#pragma unroll
        for (int aa = 0; aa < 16; aa++) {
            const int rr = 2 * aa + rh;
            if (rr < nr) {
                const int row = __builtin_amdgcn_readfirstlane(list[rc + rr]);
                out[(size_t)row * VOC + v] = acc[aa] + bv;
            }
        }
    }
    if (m == 0 && rh == 0) {
        const int nz = lists[386];
        const int* zl = lists + 256;
        for (int i = 0; i < nz; i++)
            out[(size_t)zl[i] * VOC + v] = 0.f;
    }
}

extern "C" void kernel_launch(void* const* d_in, const int* in_sizes, int n_in,
                              void* d_out, int out_size, void* d_ws, size_t ws_size,
                              hipStream_t stream) {
    const float* embed = (const float*)d_in[0];
    const float* Wpar  = (const float*)d_in[1];
    const float* bpar  = (const float*)d_in[2];
    const float* Wmu   = (const float*)d_in[3];
    const float* bmu   = (const float*)d_in[4];
    const float* Wlv   = (const float*)d_in[5];
    const float* blv   = (const float*)d_in[6];
    const float* W1    = (const float*)d_in[7];
    const float* b1    = (const float*)d_in[8];
    const float* W2    = (const float*)d_in[9];
    const float* b2    = (const float*)d_in[10];
    const float* Wl    = (const float*)d_in[11];
    const float* bl    = (const float*)d_in[12];
    const float* Wp    = (const float*)d_in[13];
    const float* bp    = (const float*)d_in[14];
    const float* eps   = (const float*)d_in[15];
    const int*  values = (const int*)d_in[16];

    float* ws = (float*)d_ws;
    float* h       = ws;                    // 255*256 = 65280
    float* Wcomb   = ws + 65408;            // 65536
    float* bcomb   = ws + 130944;           // 256
    float* Hrec    = ws + 131200;           // 32768
    float* Co1     = ws + 163968;           // 32768
    int*   rowflag = (int*)(ws + 196736);   // 128
    float* Wq_par  = ws + 196864;           // 196608
    float* Wq_mu   = ws + 393472;           // 32768
    float* Wq_lv   = ws + 426240;           // 32768
    float* Wq_w2   = ws + 459008;           // 65536
    int*   lists   = (int*)(ws + 524544);   // 387 ints
    float* out = (float*)d_out;

    // prep: wcomb (256) + Wpar pack (96) + mu/lv pack (32) + W2 pack (32)
    prep_kernel<<<416, 512, 0, stream>>>(Wp, W2, b2, bp, Wpar, Wmu, Wlv,
                                         Wcomb, bcomb, Wq_par, Wq_mu, Wq_lv, Wq_w2);

    // encoder: levels 8+7 fused (64 blocks), then level-split tail
    enc2<<<64, 1024, 0, stream>>>(embed, values, Wq_par, bpar, h, 63);
    enc_lvl<<<64, 256, 0, stream>>>(embed, values, Wq_par, bpar, h, 31, 1); // 32 nodes xS2
    enc_lvl<<<64, 256, 0, stream>>>(embed, values, Wq_par, bpar, h, 15, 2); // 16 nodes xS4
    enc_lvl<<<64, 256, 0, stream>>>(embed, values, Wq_par, bpar, h,  7, 3); //  8 nodes xS8
    enc_lvl<<<64, 256, 0, stream>>>(embed, values, Wq_par, bpar, h,  3, 4); //  4 nodes xS16
    enc_lvl<<<32, 256, 0, stream>>>(embed, values, Wq_par, bpar, h,  1, 4); //  2 nodes xS16
    enc_lvl<<<16, 256, 0, stream>>>(embed, values, Wq_par, bpar, h,  0, 4); //  1 node  xS16

    // decoder recurrence with fused head (mu/lv/z computed in-kernel)
    recur_kernel<<<1, 512, 0, stream>>>(W1, b1, W2, b2, Wcomb, bcomb, h,
                                        Wq_mu, bmu, Wq_lv, blv, eps, out,
                                        Hrec, rowflag);

    co1_kernel<<<129, 256, 0, stream>>>(Hrec, Wq_w2, b2, rowflag, Co1, lists);
    value_kernel<<<dim3(250, 2), 256, 0, stream>>>(Co1, lists, Wl, bl, Wp, bp, out);
}